// Round 7
// baseline (338.278 us; speedup 1.0000x reference)
//
#include <hip/hip_runtime.h>
#include <hip/hip_bf16.h>

// RGCN: 2-layer relational GCN + L2 normalize.
// R14: k_fused LDS 80KB -> 32KB for occupancy: B operands read direct from
//      global (Bpk is L2-resident, fragment-ordered, coalesced); epilogue-2
//      done in two 64-row half-passes through the single 32KB buffer.
//      Everything else unchanged from R13 (passed, 330.9us).

typedef unsigned int uint;
typedef unsigned short ushort;
typedef __attribute__((ext_vector_type(8))) short short8;
typedef __attribute__((ext_vector_type(16))) float floatx16;
typedef __attribute__((ext_vector_type(2))) float f32x2;
typedef __attribute__((ext_vector_type(4))) float f32x4;
typedef __attribute__((ext_vector_type(4))) uint u32x4;

#define IN_CH  128
#define OUT_CH 64
#define SCAN_CHUNK 2048
#define EPB 8192          // edges per partition block
#define KPB 512           // keys per bucket (256 nodes x 2 rels)
#define MAXBK 400         // bucket counters (NBK=391)

__device__ __forceinline__ ushort f2bf(float f) {
    uint u = __float_as_uint(f);
    u += 0x7FFF + ((u >> 16) & 1);
    return (ushort)(u >> 16);
}
__device__ __forceinline__ float bflo(uint u) { return __uint_as_float(u << 16); }
__device__ __forceinline__ float bfhi(uint u) { return __uint_as_float(u & 0xFFFF0000u); }

// ---------------- scans ----------------

__global__ void k_scan_a(const int* __restrict__ deg, int* __restrict__ offs,
                         int* __restrict__ bsums, int n) {
    __shared__ int sdata[256];
    int b = blockIdx.x, t = threadIdx.x;
    int base = b * SCAN_CHUNK + t * 8;
    int v[8];
    int sum = 0;
#pragma unroll
    for (int i = 0; i < 8; i++) {
        int idx = base + i;
        int x = (idx < n) ? deg[idx] : 0;
        v[i] = sum;
        sum += x;
    }
    sdata[t] = sum;
    __syncthreads();
    for (int ofs = 1; ofs < 256; ofs <<= 1) {
        int val = sdata[t];
        int add = (t >= ofs) ? sdata[t - ofs] : 0;
        __syncthreads();
        sdata[t] = val + add;
        __syncthreads();
    }
    int texcl = (t == 0) ? 0 : sdata[t - 1];
    if (t == 255) bsums[b] = sdata[255];
#pragma unroll
    for (int i = 0; i < 8; i++) {
        int idx = base + i;
        if (idx < n) offs[idx] = texcl + v[i];
    }
}

// wave-parallel exclusive scan of block sums (nb=38 << 64); serial fallback.
__global__ void k_scan_b(int* __restrict__ bsums, int* __restrict__ offs, int nb, int n) {
    int t = threadIdx.x;
    if (nb <= 64) {
        int v = (t < nb) ? bsums[t] : 0;
        int s = v;
#pragma unroll
        for (int d = 1; d < 64; d <<= 1) {
            int u = __shfl_up(s, d, 64);
            if (t >= d) s += u;
        }
        if (t < nb) bsums[t] = s - v;
        if (t == 63) offs[n] = s;
    } else if (t == 0) {
        int run = 0;
        for (int b = 0; b < nb; b++) {
            int x = bsums[b];
            bsums[b] = run;
            run += x;
        }
        offs[n] = run;
    }
}

// stage entry: (key & 511) << 23 | src   (src < 2^23)
// basebb is chunk-local; bsums[i>>11] applied inline.
__global__ void k_part(const int* __restrict__ src, const int* __restrict__ dst,
                       const int* __restrict__ et, const int* __restrict__ basebb,
                       const int* __restrict__ bsums,
                       uint* __restrict__ stage, int E, int NBK, int NBLK) {
    __shared__ int cnt[MAXBK];
    __shared__ int basel[MAXBK];
    int tid = threadIdx.x, blk = blockIdx.x;
    for (int b = tid; b < NBK; b += 256) {
        cnt[b] = 0;
        int i = b * NBLK + blk;
        basel[b] = basebb[i] + bsums[i >> 11];
    }
    __syncthreads();
    int base = blk * EPB;
#pragma unroll 4
    for (int i = 0; i < EPB / 256; i++) {
        int e = base + i * 256 + tid;
        if (e < E) {
            int s = src[e];
            int key = 2 * dst[e] + et[e];
            int bk = key >> 9;
            int r = atomicAdd(&cnt[bk], 1);
            stage[basel[bk] + r] = ((uint)(key & 511) << 23) | (uint)s;
        }
    }
}

// fine sort within 512-key bucket -> offs (global ends) + esrc.
__global__ void k_fine(const uint* __restrict__ stage, const int* __restrict__ basebb,
                       const int* __restrict__ bsums,
                       int* __restrict__ offs, int* __restrict__ esrc,
                       int E, int NBK, int NBLK) {
    __shared__ int kcnt[KPB];
    __shared__ int kcur[KPB];
    __shared__ int ssum[256];
    int tid = threadIdx.x, b = blockIdx.x;
    int i0 = b * NBLK;
    int start = basebb[i0] + bsums[i0 >> 11];
    int endB = E;
    if (b != NBK - 1) {
        int i1 = (b + 1) * NBLK;
        endB = basebb[i1] + bsums[i1 >> 11];
    }
    int size = endB - start;

    kcnt[tid] = 0;
    kcnt[tid + 256] = 0;
    __syncthreads();
    for (int i = tid; i < size; i += 256)
        atomicAdd(&kcnt[stage[start + i] >> 23], 1);
    __syncthreads();
    int v0 = kcnt[2 * tid], v1 = kcnt[2 * tid + 1];
    ssum[tid] = v0 + v1;
    __syncthreads();
    for (int ofs = 1; ofs < 256; ofs <<= 1) {
        int val = ssum[tid];
        int add = (tid >= ofs) ? ssum[tid - ofs] : 0;
        __syncthreads();
        ssum[tid] = val + add;
        __syncthreads();
    }
    int texcl = (tid == 0) ? 0 : ssum[tid - 1];
    kcur[2 * tid] = texcl;
    kcur[2 * tid + 1] = texcl + v0;
    offs[(b << 9) + 2 * tid] = start + texcl + v0;
    offs[(b << 9) + 2 * tid + 1] = start + texcl + v0 + v1;
    __syncthreads();
    for (int i = tid; i < size; i += 256) {
        uint p = stage[start + i];
        int r = atomicAdd(&kcur[p >> 23], 1);
        esrc[start + r] = (int)(p & 0x7FFFFFu);
    }
}

// --- merged: edge count (blocks 0..NBLK) + weight pre-pack + zeros + cvt ---

__device__ __forceinline__ uint4 pack8(const ushort* o) {
    uint4 v;
    v.x = (uint)o[0] | ((uint)o[1] << 16);
    v.y = (uint)o[2] | ((uint)o[3] << 16);
    v.z = (uint)o[4] | ((uint)o[5] << 16);
    v.w = (uint)o[6] | ((uint)o[7] << 16);
    return v;
}

__global__ void k_pre(const int* __restrict__ dst, const int* __restrict__ et,
                      int* __restrict__ cntblk, int E, int NBK, int NBLK,
                      const float* __restrict__ x, uint4* __restrict__ xb, int n8,
                      const float* __restrict__ W1root, const float* __restrict__ W1rel,
                      const float* __restrict__ W2root, const float* __restrict__ W2rel,
                      uint4* __restrict__ Bpk1, uint4* __restrict__ Bpk2,
                      uint* __restrict__ xzero, uint* __restrict__ t2zero) {
    __shared__ int cnt[MAXBK];
    int tid = threadIdx.x;
    if ((int)blockIdx.x < NBLK) {
        int blk = blockIdx.x;
        for (int b = tid; b < NBK; b += 256) cnt[b] = 0;
        __syncthreads();
        int base = blk * EPB;
#pragma unroll 4
        for (int i = 0; i < EPB / 256; i++) {
            int e = base + i * 256 + tid;
            if (e < E) {
                int key = 2 * dst[e] + et[e];
                atomicAdd(&cnt[key >> 9], 1);
            }
        }
        __syncthreads();
        for (int b = tid; b < NBK; b += 256) cntblk[b * NBLK + blk] = cnt[b];
        return;
    }
    int bid = blockIdx.x - NBLK;
    if (bid < 40) {
        if (bid == 0) {
            if (tid < 64) xzero[tid] = 0;        // 256B zero row of xb
            if (tid < 96) t2zero[tid] = 0;       // 384B zero row of t2
        }
        int idx = bid * 256 + tid;
        ushort o[8];
        if (idx < 6144) {
            int id = idx;
            int ct = id >> 11;                 // K-segment: 0 root, 1 rel0, 2 rel1
            int c = id & 2047;
            int gn = c >> 9, s = (c >> 6) & 7, h = (c >> 5) & 1, n = c & 31;
            int k0 = s * 16 + h * 8;
            int col = gn * 32 + n;
            const float* W = (ct == 0) ? W1root : (W1rel + (size_t)(ct - 1) * 16384);
#pragma unroll
            for (int j = 0; j < 8; j++) o[j] = f2bf(W[(k0 + j) * 128 + col]);
            Bpk1[id] = pack8(o);
        } else {
            int id = idx - 6144;
            int ct = id >> 11;                 // col tile 0..1 over 256 padded cols
            int c = id & 2047;
            int gn = c >> 9, s = (c >> 6) & 7, h = (c >> 5) & 1, n = c & 31;
            int k0 = s * 16 + h * 8;
            int colg = ct * 128 + gn * 32 + n;
#pragma unroll
            for (int j = 0; j < 8; j++) {
                float f = 0.f;
                if (colg < 64)       f = W2root[(k0 + j) * 64 + colg];
                else if (colg < 128) f = W2rel[(k0 + j) * 64 + (colg - 64)];
                else if (colg < 192) f = W2rel[8192 + (k0 + j) * 64 + (colg - 128)];
                o[j] = f2bf(f);
            }
            Bpk2[id] = pack8(o);
        }
    } else {
        int i = (bid - 40) * 256 + tid;
        if (i >= n8) return;
        const f32x4* xp = (const f32x4*)x;
        f32x4 f0 = __builtin_nontemporal_load(&xp[(size_t)i * 2]);
        f32x4 f1 = __builtin_nontemporal_load(&xp[(size_t)i * 2 + 1]);
        uint4 o;
        o.x = (uint)f2bf(f0.x) | ((uint)f2bf(f0.y) << 16);
        o.y = (uint)f2bf(f0.z) | ((uint)f2bf(f0.w) << 16);
        o.z = (uint)f2bf(f1.x) | ((uint)f2bf(f1.y) << 16);
        o.w = (uint)f2bf(f1.z) | ((uint)f2bf(f1.w) << 16);
        xb[i] = o;
    }
}

// ------- layer-1 gather: 2 nodes/wave, mean(xb[src]) per rel -> S1 ---------

__global__ __launch_bounds__(256)
void k_agg(const int* __restrict__ offs, const int* __restrict__ esrc,
           const uint4* __restrict__ xb4, uint* __restrict__ S, int N) {
    int wid = (int)((blockIdx.x * 256L + threadIdx.x) >> 5);
    int l = threadIdx.x & 31;
    if (wid >= N) return;
    int q = l >> 4, c = l & 15;

    int beg0 = (wid == 0) ? 0 : offs[2 * wid - 1];
    int end0 = offs[2 * wid], end1 = offs[2 * wid + 1];

    u32x4 o = {0, 0, 0, 0};
#pragma unroll
    for (int r = 0; r < 2; r++) {
        int beg = r ? end0 : beg0;
        int end = r ? end1 : end0;
        f32x2 a0 = {0.f, 0.f}, a1 = {0.f, 0.f}, a2 = {0.f, 0.f}, a3 = {0.f, 0.f};
        for (int c0 = beg; c0 < end; c0 += 32) {
            int myid = (c0 + l < end) ? __builtin_nontemporal_load(&esrc[c0 + l]) : N;
            int m = min(32, end - c0);
            for (int eb = 0; eb < m; eb += 4) {
#pragma unroll
                for (int j = 0; j < 2; j++) {
                    int id = __shfl(myid, eb + 2 * j + q, 32);
                    uint4 v = xb4[(uint)id * 16u + (uint)c];
                    a0 += (f32x2){bflo(v.x), bfhi(v.x)};
                    a1 += (f32x2){bflo(v.y), bfhi(v.y)};
                    a2 += (f32x2){bflo(v.z), bfhi(v.z)};
                    a3 += (f32x2){bflo(v.w), bfhi(v.w)};
                }
            }
        }
        a0.x += __shfl_xor(a0.x, 16, 32); a0.y += __shfl_xor(a0.y, 16, 32);
        a1.x += __shfl_xor(a1.x, 16, 32); a1.y += __shfl_xor(a1.y, 16, 32);
        a2.x += __shfl_xor(a2.x, 16, 32); a2.y += __shfl_xor(a2.y, 16, 32);
        a3.x += __shfl_xor(a3.x, 16, 32); a3.y += __shfl_xor(a3.y, 16, 32);
        if (q == r) {
            float inv = (end > beg) ? 1.0f / (float)(end - beg) : 0.f;
            o.x = (uint)f2bf(a0.x * inv) | ((uint)f2bf(a0.y * inv) << 16);
            o.y = (uint)f2bf(a1.x * inv) | ((uint)f2bf(a1.y * inv) << 16);
            o.z = (uint)f2bf(a2.x * inv) | ((uint)f2bf(a2.y * inv) << 16);
            o.w = (uint)f2bf(a3.x * inv) | ((uint)f2bf(a3.y * inv) << 16);
        }
    }
    u32x4* Sp = (u32x4*)S;
    __builtin_nontemporal_store(o, &Sp[(size_t)wid * 32 + q * 16 + c]);
}

// ------- fused GEMM: t2 = relu([xb|S1]@Bpk1 + b1) @ Bpk2 -------------------
// 32KB LDS total. Phase 1 (K=384): A staged in LDS, B direct from global
// (Bpk fragment-ordered, L2-resident). Epilogue-1 writes h-tile into the
// same LDS in A-fragment layout. Phase 2 (K=128, 192 cols): B2 from global.
// Epilogue-2: two 64-row transpose half-passes through the same 32KB.

__global__ __launch_bounds__(256)
void k_fused(const ushort* __restrict__ xb, const ushort* __restrict__ S1,
             const ushort* __restrict__ Bpk1, const float* __restrict__ b1,
             const ushort* __restrict__ Bpk2, ushort* __restrict__ Out, int N) {
    __shared__ ushort SH[16384];          // 32 KB: A-tile / h-frag / C half
    ushort* Alds = SH;

    const int tid = threadIdx.x;
    const int lane = tid & 63;
    const int w = tid >> 6;
    const int wm = w >> 1, wn = w & 1;
    const int rowBase = blockIdx.x * 128;

    const short8* B1 = (const short8*)Bpk1;
    const short8* B2 = (const short8*)Bpk2;

    floatx16 acc[2][2] = {};

#pragma unroll
    for (int seg = 0; seg < 3; seg++) {
        const ushort* Ap = (seg == 0) ? xb : S1;
        const int stride = (seg == 0) ? 128 : 256;
        const int aoff = (seg == 2) ? 128 : 0;
#pragma unroll
        for (int i = 0; i < 8; i++) {
            int c = tid + i * 256;
            int m = c & 31, hh = (c >> 5) & 1, s = (c >> 6) & 7, g = c >> 9;
            int row = rowBase + g * 32 + m;
            if (row >= N) row = N - 1;
            int kc = s * 2 + hh;
            ((uint4*)Alds)[c] = *(const uint4*)(Ap + (size_t)row * stride + aoff + kc * 8);
        }
        __syncthreads();
#pragma unroll
        for (int s = 0; s < 8; s++) {
            short8 a0 = *(const short8*)&Alds[(((wm * 2 + 0) * 8 + s) * 64 + lane) * 8];
            short8 a1 = *(const short8*)&Alds[(((wm * 2 + 1) * 8 + s) * 64 + lane) * 8];
            short8 b0 = B1[seg * 2048 + ((wn * 2 + 0) * 8 + s) * 64 + lane];
            short8 b1f = B1[seg * 2048 + ((wn * 2 + 1) * 8 + s) * 64 + lane];
            acc[0][0] = __builtin_amdgcn_mfma_f32_32x32x16_bf16(a0, b0, acc[0][0], 0, 0, 0);
            acc[0][1] = __builtin_amdgcn_mfma_f32_32x32x16_bf16(a0, b1f, acc[0][1], 0, 0, 0);
            acc[1][0] = __builtin_amdgcn_mfma_f32_32x32x16_bf16(a1, b0, acc[1][0], 0, 0, 0);
            acc[1][1] = __builtin_amdgcn_mfma_f32_32x32x16_bf16(a1, b1f, acc[1][1], 0, 0, 0);
        }
        __syncthreads();
    }

    // ---- epilogue-1: h-tile -> Alds in A-fragment layout (bias+relu)
    {
        const int qr = 4 * (lane >> 5);
        const int cl = lane & 31;
        float bb[2];
#pragma unroll
        for (int nt = 0; nt < 2; nt++) bb[nt] = b1[wn * 64 + nt * 32 + cl];
#pragma unroll
        for (int mt = 0; mt < 2; mt++)
#pragma unroll
            for (int nt = 0; nt < 2; nt++) {
                int col = wn * 64 + nt * 32 + cl;
                int kc = col >> 3, j = col & 7;
                int s = kc >> 1, hh = kc & 1;
                int base = (((wm * 2 + mt) * 8 + s) * 64 + hh * 32) * 8 + j;
#pragma unroll
                for (int reg = 0; reg < 16; reg++) {
                    int rl = (reg & 3) + 8 * (reg >> 2) + qr;
                    float v = fmaxf(acc[mt][nt][reg] + bb[nt], 0.f);
                    Alds[base + rl * 8] = f2bf(v);
                }
            }
    }
    __syncthreads();

    // ---- phase 2: K=128, 192 cols; B2 direct from global
    floatx16 acc2[2][3] = {};
#pragma unroll
    for (int s = 0; s < 8; s++) {
        short8 a0 = *(const short8*)&Alds[(((wm * 2 + 0) * 8 + s) * 64 + lane) * 8];
        short8 a1 = *(const short8*)&Alds[(((wm * 2 + 1) * 8 + s) * 64 + lane) * 8];
        short8 b0 = B2[((wn * 3 + 0) * 8 + s) * 64 + lane];
        short8 b1v = B2[((wn * 3 + 1) * 8 + s) * 64 + lane];
        short8 b2v = B2[((wn * 3 + 2) * 8 + s) * 64 + lane];
        acc2[0][0] = __builtin_amdgcn_mfma_f32_32x32x16_bf16(a0, b0, acc2[0][0], 0, 0, 0);
        acc2[0][1] = __builtin_amdgcn_mfma_f32_32x32x16_bf16(a0, b1v, acc2[0][1], 0, 0, 0);
        acc2[0][2] = __builtin_amdgcn_mfma_f32_32x32x16_bf16(a0, b2v, acc2[0][2], 0, 0, 0);
        acc2[1][0] = __builtin_amdgcn_mfma_f32_32x32x16_bf16(a1, b0, acc2[1][0], 0, 0, 0);
        acc2[1][1] = __builtin_amdgcn_mfma_f32_32x32x16_bf16(a1, b1v, acc2[1][1], 0, 0, 0);
        acc2[1][2] = __builtin_amdgcn_mfma_f32_32x32x16_bf16(a1, b2v, acc2[1][2], 0, 0, 0);
    }

    // ---- epilogue-2: two 64-row transpose half-passes (25.6KB each)
    ushort* Clds = SH;
    const int qr = 4 * (lane >> 5);
    const int cl = lane & 31;
#pragma unroll
    for (int half = 0; half < 2; half++) {
        __syncthreads();                  // Alds/Clds reads of prev step done
        if (wm == half) {
#pragma unroll
            for (int mt = 0; mt < 2; mt++)
#pragma unroll
                for (int nt = 0; nt < 3; nt++) {
#pragma unroll
                    for (int reg = 0; reg < 16; reg++) {
                        int rl = (reg & 3) + 8 * (reg >> 2) + qr;
                        Clds[(mt * 32 + rl) * 200 + wn * 96 + nt * 32 + cl] =
                            f2bf(acc2[mt][nt][reg]);
                    }
                }
        }
        __syncthreads();
        int r = tid >> 2, q4 = tid & 3;
        int grow = rowBase + half * 64 + r;
        if (grow < N) {
#pragma unroll
            for (int k = 0; k < 6; k++) {
                int c0 = q4 * 48 + k * 8;
                uint4 v = *(const uint4*)&Clds[r * 200 + c0];
                *(uint4*)(Out + (size_t)grow * 192 + c0) = v;
            }
        }
    }
}

// ------- layer-2 fused: gather-mean of t2 + root + bias + L2 norm ----------

__global__ __launch_bounds__(256)
void k_final(const ushort* __restrict__ T2, const float* __restrict__ b2,
             const int* __restrict__ offs, const int* __restrict__ esrc,
             float* __restrict__ out, int N) {
    int wid = (int)((blockIdx.x * 256L + threadIdx.x) >> 3);
    int c = threadIdx.x & 7;
    if (wid >= N) return;
    const uint4* Tb = (const uint4*)T2;   // row stride 24 uint4

    int beg0 = (wid == 0) ? 0 : offs[2 * wid - 1];
    int end0 = offs[2 * wid], end1 = offs[2 * wid + 1];

    f32x2 t0 = {0.f, 0.f}, t1 = {0.f, 0.f}, t2v = {0.f, 0.f}, t3v = {0.f, 0.f};
#pragma unroll
    for (int r = 0; r < 2; r++) {
        int beg = r ? end0 : beg0;
        int end = r ? end1 : end0;
        if (end > beg) {
            f32x2 a0 = {0.f, 0.f}, a1 = {0.f, 0.f}, a2 = {0.f, 0.f}, a3 = {0.f, 0.f};
            uint bc = 8u + 8u * (uint)r + (uint)c;
            for (int c0 = beg; c0 < end; c0 += 8) {
                int myid = (c0 + c < end) ? __builtin_nontemporal_load(&esrc[c0 + c]) : N;
                int m = min(8, end - c0);
                for (int eb = 0; eb < m; eb += 4) {
                    uint4 v[4];
#pragma unroll
                    for (int j = 0; j < 4; j++) {
                        int id = __shfl(myid, eb + j, 8);
                        v[j] = Tb[(uint)id * 24u + bc];
                    }
#pragma unroll
                    for (int j = 0; j < 4; j++) {
                        a0 += (f32x2){bflo(v[j].x), bfhi(v[j].x)};
                        a1 += (f32x2){bflo(v[j].y), bfhi(v[j].y)};
                        a2 += (f32x2){bflo(v[j].z), bfhi(v[j].z)};
                        a3 += (f32x2){bflo(v[j].w), bfhi(v[j].w)};
                    }
                }
            }
            float inv = 1.0f / (float)(end - beg);
            t0 += a0 * inv; t1 += a1 * inv; t2v += a2 * inv; t3v += a3 * inv;
        }
    }
    uint4 ru = Tb[(uint)wid * 24u + (uint)c];
    float4 bbA = *(const float4*)(b2 + 8 * c);
    float4 bbB = *(const float4*)(b2 + 8 * c + 4);
    float v0 = bflo(ru.x) + bbA.x + t0.x;
    float v1 = bfhi(ru.x) + bbA.y + t0.y;
    float v2 = bflo(ru.y) + bbA.z + t1.x;
    float v3 = bfhi(ru.y) + bbA.w + t1.y;
    float v4 = bflo(ru.z) + bbB.x + t2v.x;
    float v5 = bfhi(ru.z) + bbB.y + t2v.y;
    float v6 = bflo(ru.w) + bbB.z + t3v.x;
    float v7 = bfhi(ru.w) + bbB.w + t3v.y;
    float sq = v0 * v0 + v1 * v1 + v2 * v2 + v3 * v3
             + v4 * v4 + v5 * v5 + v6 * v6 + v7 * v7;
#pragma unroll
    for (int d = 1; d <= 4; d <<= 1) sq += __shfl_xor(sq, d, 8);
    float rn = 1.0f / fmaxf(sqrtf(sq), 1e-12f);
    f32x4 oA = {v0 * rn, v1 * rn, v2 * rn, v3 * rn};
    f32x4 oB = {v4 * rn, v5 * rn, v6 * rn, v7 * rn};
    f32x4* op = (f32x4*)(out + (size_t)wid * 64 + 8 * c);
    __builtin_nontemporal_store(oA, op);
    __builtin_nontemporal_store(oB, op + 1);
}

// ---------------- launch ----------------

extern "C" void kernel_launch(void* const* d_in, const int* in_sizes, int n_in,
                              void* d_out, int out_size, void* d_ws, size_t ws_size,
                              hipStream_t stream) {
    const float* x      = (const float*)d_in[0];
    const int*   ei     = (const int*)d_in[1];
    const int*   etype  = (const int*)d_in[2];
    const float* W1rel  = (const float*)d_in[3];
    const float* W1root = (const float*)d_in[4];
    const float* b1     = (const float*)d_in[5];
    const float* W2rel  = (const float*)d_in[6];
    const float* W2root = (const float*)d_in[7];
    const float* b2     = (const float*)d_in[8];
    float* out = (float*)d_out;

    const int N = in_sizes[0] / IN_CH;   // 100000
    const int E = in_sizes[2];           // 1600000
    const int NKEY = 2 * N;
    const int NBK  = (NKEY + KPB - 1) / KPB;   // 391 buckets
    const int NBLK = (E + EPB - 1) / EPB;      // 196 partition blocks
    const int NSC  = NBK * NBLK;

    const int* src = ei;
    const int* dst = ei + E;

    char* base = (char*)d_ws;
    size_t off = 0;
    auto carve = [&](size_t bytes) -> void* {
        void* p = base + off;
        off = (off + bytes + 511) & ~(size_t)511;
        return p;
    };
    ushort* xb    = (ushort*)carve((size_t)(N + 1) * 128 * sizeof(ushort)); // +zero row
    ushort* S1    = (ushort*)carve((size_t)N * 256 * sizeof(ushort));       // 51.2MB
    ushort* t2    = (ushort*)carve((size_t)(N + 1) * 192 * sizeof(ushort)); // +zero row
    int*    esrc  = (int*)carve((size_t)E * sizeof(int));
    uint*   stage = (uint*)carve((size_t)E * sizeof(uint));                 // 6.4MB
    int*    offs  = (int*)carve((size_t)NBK * KPB * sizeof(int));
    int*    cntblk= (int*)carve((size_t)NSC * sizeof(int));
    int*    basebb= (int*)carve((size_t)(NSC + 1) * sizeof(int));
    int     NB    = (NSC + SCAN_CHUNK - 1) / SCAN_CHUNK;
    int*    bsums = (int*)carve((size_t)NB * sizeof(int));
    uint4*  Bpk1  = (uint4*)carve(6144 * sizeof(uint4));
    uint4*  Bpk2  = (uint4*)carve(4096 * sizeof(uint4));
    (void)ws_size; (void)n_in; (void)out_size;

    int n8 = N * 16;
    int preBlocks = NBLK + 40 + (n8 + 255) / 256;

    // count + cvt + prep + zero rows (count overlaps cvt/prep)
    k_pre<<<preBlocks, 256, 0, stream>>>(dst, etype, cntblk, E, NBK, NBLK,
                                         x, (uint4*)xb, n8,
                                         W1root, W1rel, W2root, W2rel,
                                         Bpk1, Bpk2,
                                         (uint*)(xb + (size_t)N * 128),
                                         (uint*)(t2 + (size_t)N * 192));

    // radix partition + fine sort
    k_scan_a<<<NB, 256, 0, stream>>>(cntblk, basebb, bsums, NSC);
    k_scan_b<<<1, 64, 0, stream>>>(bsums, basebb, NB, NSC);
    k_part<<<NBLK, 256, 0, stream>>>(src, dst, etype, basebb, bsums, stage, E, NBK, NBLK);
    k_fine<<<NBK, 256, 0, stream>>>(stage, basebb, bsums, offs, esrc, E, NBK, NBLK);

    int rowTiles = (N + 127) / 128;
    int aggBlocks = (N + 7) / 8;         // 2 nodes/wave, 8 nodes/block
    int finBlocks = (N + 31) / 32;       // 8 nodes/wave, 32 nodes/block

    // Layer 1 gather, then fused GEMM1+GEMMT -> t2 (h never hits memory)
    k_agg<<<aggBlocks, 256, 0, stream>>>(offs, esrc, (const uint4*)xb, (uint*)S1, N);
    k_fused<<<rowTiles, 256, 0, stream>>>(xb, S1, (const ushort*)Bpk1, b1,
                                          (const ushort*)Bpk2, t2, N);

    // Layer 2 fused gather + L2 norm
    k_final<<<finBlocks, 256, 0, stream>>>(t2, b2, offs, esrc, out, N);
}

// Round 8
// 310.381 us; speedup vs baseline: 1.0899x; 1.0899x over previous
//
#include <hip/hip_runtime.h>
#include <hip/hip_bf16.h>

// RGCN: 2-layer relational GCN + L2 normalize.
// R15: k_fused rebuilt as 512-thread / 8-wave blocks, R13's proven 80KB LDS
//      layout (A 32KB + B 48KB staged in LDS). 2 blocks/CU -> 16 waves/CU
//      (2x R13) for latency hiding; wave layout wm 0..3 x wn 0..1.
//      k_agg: S1 store no longer nontemporal (keep S1 L3-resident for fused).
//      Everything else unchanged from R13/R14 (passed).

typedef unsigned int uint;
typedef unsigned short ushort;
typedef __attribute__((ext_vector_type(8))) short short8;
typedef __attribute__((ext_vector_type(16))) float floatx16;
typedef __attribute__((ext_vector_type(2))) float f32x2;
typedef __attribute__((ext_vector_type(4))) float f32x4;
typedef __attribute__((ext_vector_type(4))) uint u32x4;

#define IN_CH  128
#define OUT_CH 64
#define SCAN_CHUNK 2048
#define EPB 8192          // edges per partition block
#define KPB 512           // keys per bucket (256 nodes x 2 rels)
#define MAXBK 400         // bucket counters (NBK=391)

__device__ __forceinline__ ushort f2bf(float f) {
    uint u = __float_as_uint(f);
    u += 0x7FFF + ((u >> 16) & 1);
    return (ushort)(u >> 16);
}
__device__ __forceinline__ float bflo(uint u) { return __uint_as_float(u << 16); }
__device__ __forceinline__ float bfhi(uint u) { return __uint_as_float(u & 0xFFFF0000u); }

// ---------------- scans ----------------

__global__ void k_scan_a(const int* __restrict__ deg, int* __restrict__ offs,
                         int* __restrict__ bsums, int n) {
    __shared__ int sdata[256];
    int b = blockIdx.x, t = threadIdx.x;
    int base = b * SCAN_CHUNK + t * 8;
    int v[8];
    int sum = 0;
#pragma unroll
    for (int i = 0; i < 8; i++) {
        int idx = base + i;
        int x = (idx < n) ? deg[idx] : 0;
        v[i] = sum;
        sum += x;
    }
    sdata[t] = sum;
    __syncthreads();
    for (int ofs = 1; ofs < 256; ofs <<= 1) {
        int val = sdata[t];
        int add = (t >= ofs) ? sdata[t - ofs] : 0;
        __syncthreads();
        sdata[t] = val + add;
        __syncthreads();
    }
    int texcl = (t == 0) ? 0 : sdata[t - 1];
    if (t == 255) bsums[b] = sdata[255];
#pragma unroll
    for (int i = 0; i < 8; i++) {
        int idx = base + i;
        if (idx < n) offs[idx] = texcl + v[i];
    }
}

// wave-parallel exclusive scan of block sums (nb=38 << 64); serial fallback.
__global__ void k_scan_b(int* __restrict__ bsums, int* __restrict__ offs, int nb, int n) {
    int t = threadIdx.x;
    if (nb <= 64) {
        int v = (t < nb) ? bsums[t] : 0;
        int s = v;
#pragma unroll
        for (int d = 1; d < 64; d <<= 1) {
            int u = __shfl_up(s, d, 64);
            if (t >= d) s += u;
        }
        if (t < nb) bsums[t] = s - v;
        if (t == 63) offs[n] = s;
    } else if (t == 0) {
        int run = 0;
        for (int b = 0; b < nb; b++) {
            int x = bsums[b];
            bsums[b] = run;
            run += x;
        }
        offs[n] = run;
    }
}

// stage entry: (key & 511) << 23 | src   (src < 2^23)
// basebb is chunk-local; bsums[i>>11] applied inline.
__global__ void k_part(const int* __restrict__ src, const int* __restrict__ dst,
                       const int* __restrict__ et, const int* __restrict__ basebb,
                       const int* __restrict__ bsums,
                       uint* __restrict__ stage, int E, int NBK, int NBLK) {
    __shared__ int cnt[MAXBK];
    __shared__ int basel[MAXBK];
    int tid = threadIdx.x, blk = blockIdx.x;
    for (int b = tid; b < NBK; b += 256) {
        cnt[b] = 0;
        int i = b * NBLK + blk;
        basel[b] = basebb[i] + bsums[i >> 11];
    }
    __syncthreads();
    int base = blk * EPB;
#pragma unroll 4
    for (int i = 0; i < EPB / 256; i++) {
        int e = base + i * 256 + tid;
        if (e < E) {
            int s = src[e];
            int key = 2 * dst[e] + et[e];
            int bk = key >> 9;
            int r = atomicAdd(&cnt[bk], 1);
            stage[basel[bk] + r] = ((uint)(key & 511) << 23) | (uint)s;
        }
    }
}

// fine sort within 512-key bucket -> offs (global ends) + esrc.
__global__ void k_fine(const uint* __restrict__ stage, const int* __restrict__ basebb,
                       const int* __restrict__ bsums,
                       int* __restrict__ offs, int* __restrict__ esrc,
                       int E, int NBK, int NBLK) {
    __shared__ int kcnt[KPB];
    __shared__ int kcur[KPB];
    __shared__ int ssum[256];
    int tid = threadIdx.x, b = blockIdx.x;
    int i0 = b * NBLK;
    int start = basebb[i0] + bsums[i0 >> 11];
    int endB = E;
    if (b != NBK - 1) {
        int i1 = (b + 1) * NBLK;
        endB = basebb[i1] + bsums[i1 >> 11];
    }
    int size = endB - start;

    kcnt[tid] = 0;
    kcnt[tid + 256] = 0;
    __syncthreads();
    for (int i = tid; i < size; i += 256)
        atomicAdd(&kcnt[stage[start + i] >> 23], 1);
    __syncthreads();
    int v0 = kcnt[2 * tid], v1 = kcnt[2 * tid + 1];
    ssum[tid] = v0 + v1;
    __syncthreads();
    for (int ofs = 1; ofs < 256; ofs <<= 1) {
        int val = ssum[tid];
        int add = (tid >= ofs) ? ssum[tid - ofs] : 0;
        __syncthreads();
        ssum[tid] = val + add;
        __syncthreads();
    }
    int texcl = (tid == 0) ? 0 : ssum[tid - 1];
    kcur[2 * tid] = texcl;
    kcur[2 * tid + 1] = texcl + v0;
    offs[(b << 9) + 2 * tid] = start + texcl + v0;
    offs[(b << 9) + 2 * tid + 1] = start + texcl + v0 + v1;
    __syncthreads();
    for (int i = tid; i < size; i += 256) {
        uint p = stage[start + i];
        int r = atomicAdd(&kcur[p >> 23], 1);
        esrc[start + r] = (int)(p & 0x7FFFFFu);
    }
}

// --- merged: edge count (blocks 0..NBLK) + weight pre-pack + zeros + cvt ---

__device__ __forceinline__ uint4 pack8(const ushort* o) {
    uint4 v;
    v.x = (uint)o[0] | ((uint)o[1] << 16);
    v.y = (uint)o[2] | ((uint)o[3] << 16);
    v.z = (uint)o[4] | ((uint)o[5] << 16);
    v.w = (uint)o[6] | ((uint)o[7] << 16);
    return v;
}

__global__ void k_pre(const int* __restrict__ dst, const int* __restrict__ et,
                      int* __restrict__ cntblk, int E, int NBK, int NBLK,
                      const float* __restrict__ x, uint4* __restrict__ xb, int n8,
                      const float* __restrict__ W1root, const float* __restrict__ W1rel,
                      const float* __restrict__ W2root, const float* __restrict__ W2rel,
                      uint4* __restrict__ Bpk1, uint4* __restrict__ Bpk2,
                      uint* __restrict__ xzero, uint* __restrict__ t2zero) {
    __shared__ int cnt[MAXBK];
    int tid = threadIdx.x;
    if ((int)blockIdx.x < NBLK) {
        int blk = blockIdx.x;
        for (int b = tid; b < NBK; b += 256) cnt[b] = 0;
        __syncthreads();
        int base = blk * EPB;
#pragma unroll 4
        for (int i = 0; i < EPB / 256; i++) {
            int e = base + i * 256 + tid;
            if (e < E) {
                int key = 2 * dst[e] + et[e];
                atomicAdd(&cnt[key >> 9], 1);
            }
        }
        __syncthreads();
        for (int b = tid; b < NBK; b += 256) cntblk[b * NBLK + blk] = cnt[b];
        return;
    }
    int bid = blockIdx.x - NBLK;
    if (bid < 40) {
        if (bid == 0) {
            if (tid < 64) xzero[tid] = 0;        // 256B zero row of xb
            if (tid < 96) t2zero[tid] = 0;       // 384B zero row of t2
        }
        int idx = bid * 256 + tid;
        ushort o[8];
        if (idx < 6144) {
            int id = idx;
            int ct = id >> 11;                 // K-segment: 0 root, 1 rel0, 2 rel1
            int c = id & 2047;
            int gn = c >> 9, s = (c >> 6) & 7, h = (c >> 5) & 1, n = c & 31;
            int k0 = s * 16 + h * 8;
            int col = gn * 32 + n;
            const float* W = (ct == 0) ? W1root : (W1rel + (size_t)(ct - 1) * 16384);
#pragma unroll
            for (int j = 0; j < 8; j++) o[j] = f2bf(W[(k0 + j) * 128 + col]);
            Bpk1[id] = pack8(o);
        } else {
            int id = idx - 6144;
            int ct = id >> 11;                 // col tile 0..1 over 256 padded cols
            int c = id & 2047;
            int gn = c >> 9, s = (c >> 6) & 7, h = (c >> 5) & 1, n = c & 31;
            int k0 = s * 16 + h * 8;
            int colg = ct * 128 + gn * 32 + n;
#pragma unroll
            for (int j = 0; j < 8; j++) {
                float f = 0.f;
                if (colg < 64)       f = W2root[(k0 + j) * 64 + colg];
                else if (colg < 128) f = W2rel[(k0 + j) * 64 + (colg - 64)];
                else if (colg < 192) f = W2rel[8192 + (k0 + j) * 64 + (colg - 128)];
                o[j] = f2bf(f);
            }
            Bpk2[id] = pack8(o);
        }
    } else {
        int i = (bid - 40) * 256 + tid;
        if (i >= n8) return;
        const f32x4* xp = (const f32x4*)x;
        f32x4 f0 = __builtin_nontemporal_load(&xp[(size_t)i * 2]);
        f32x4 f1 = __builtin_nontemporal_load(&xp[(size_t)i * 2 + 1]);
        uint4 o;
        o.x = (uint)f2bf(f0.x) | ((uint)f2bf(f0.y) << 16);
        o.y = (uint)f2bf(f0.z) | ((uint)f2bf(f0.w) << 16);
        o.z = (uint)f2bf(f1.x) | ((uint)f2bf(f1.y) << 16);
        o.w = (uint)f2bf(f1.z) | ((uint)f2bf(f1.w) << 16);
        xb[i] = o;
    }
}

// ------- layer-1 gather: 2 nodes/wave, mean(xb[src]) per rel -> S1 ---------

__global__ __launch_bounds__(256)
void k_agg(const int* __restrict__ offs, const int* __restrict__ esrc,
           const uint4* __restrict__ xb4, uint4* __restrict__ S4, int N) {
    int wid = (int)((blockIdx.x * 256L + threadIdx.x) >> 5);
    int l = threadIdx.x & 31;
    if (wid >= N) return;
    int q = l >> 4, c = l & 15;

    int beg0 = (wid == 0) ? 0 : offs[2 * wid - 1];
    int end0 = offs[2 * wid], end1 = offs[2 * wid + 1];

    uint4 o = make_uint4(0, 0, 0, 0);
#pragma unroll
    for (int r = 0; r < 2; r++) {
        int beg = r ? end0 : beg0;
        int end = r ? end1 : end0;
        f32x2 a0 = {0.f, 0.f}, a1 = {0.f, 0.f}, a2 = {0.f, 0.f}, a3 = {0.f, 0.f};
        for (int c0 = beg; c0 < end; c0 += 32) {
            int myid = (c0 + l < end) ? __builtin_nontemporal_load(&esrc[c0 + l]) : N;
            int m = min(32, end - c0);
            for (int eb = 0; eb < m; eb += 4) {
#pragma unroll
                for (int j = 0; j < 2; j++) {
                    int id = __shfl(myid, eb + 2 * j + q, 32);
                    uint4 v = xb4[(uint)id * 16u + (uint)c];
                    a0 += (f32x2){bflo(v.x), bfhi(v.x)};
                    a1 += (f32x2){bflo(v.y), bfhi(v.y)};
                    a2 += (f32x2){bflo(v.z), bfhi(v.z)};
                    a3 += (f32x2){bflo(v.w), bfhi(v.w)};
                }
            }
        }
        a0.x += __shfl_xor(a0.x, 16, 32); a0.y += __shfl_xor(a0.y, 16, 32);
        a1.x += __shfl_xor(a1.x, 16, 32); a1.y += __shfl_xor(a1.y, 16, 32);
        a2.x += __shfl_xor(a2.x, 16, 32); a2.y += __shfl_xor(a2.y, 16, 32);
        a3.x += __shfl_xor(a3.x, 16, 32); a3.y += __shfl_xor(a3.y, 16, 32);
        if (q == r) {
            float inv = (end > beg) ? 1.0f / (float)(end - beg) : 0.f;
            o.x = (uint)f2bf(a0.x * inv) | ((uint)f2bf(a0.y * inv) << 16);
            o.y = (uint)f2bf(a1.x * inv) | ((uint)f2bf(a1.y * inv) << 16);
            o.z = (uint)f2bf(a2.x * inv) | ((uint)f2bf(a2.y * inv) << 16);
            o.w = (uint)f2bf(a3.x * inv) | ((uint)f2bf(a3.y * inv) << 16);
        }
    }
    // S row = [rel0 128ch | rel1 128ch] = 32 uint4; normal store (L3-resident
    // for k_fused's seg1/seg2 A reads).
    S4[(size_t)wid * 32 + q * 16 + c] = o;
}

// ------- fused GEMM: t2 = relu([xb|S1]@Bpk1 + b1) @ Bpk2 -------------------
// 512 threads / 8 waves, 128-row tile, 80KB LDS (A 32KB + B 48KB) -> exactly
// 2 blocks/CU = 16 waves/CU. Wave (wm 0..3, wn 0..1): 32 rows x 64 cols in
// phase 1 (acc[2]), 32 rows x 96 cols in phase 2 (acc2[3]). h-tile lives in
// LDS in A-fragment layout between phases; h never touches global memory.

__global__ __launch_bounds__(512)
void k_fused(const ushort* __restrict__ xb, const ushort* __restrict__ S1,
             const ushort* __restrict__ Bpk1, const float* __restrict__ b1,
             const ushort* __restrict__ Bpk2, ushort* __restrict__ Out, int N) {
    __shared__ ushort SH[40960];          // 80 KB
    ushort* Alds = SH;                    // 32 KB (A-tile / h-frag)
    ushort* Blds = SH + 16384;            // 48 KB (B1 seg 32KB / B2 48KB)

    const int tid = threadIdx.x;
    const int lane = tid & 63;
    const int w = tid >> 6;               // 0..7
    const int wm = w & 3;                 // 32-row group
    const int wn = w >> 2;                // col group 0..1
    const int rowBase = blockIdx.x * 128;

    floatx16 acc[2] = {};

#pragma unroll
    for (int seg = 0; seg < 3; seg++) {
        const ushort* Ap = (seg == 0) ? xb : S1;
        const int stride = (seg == 0) ? 128 : 256;
        const int aoff = (seg == 2) ? 128 : 0;
        const uint4* Bsrc = (const uint4*)Bpk1 + seg * 2048;
#pragma unroll
        for (int i = 0; i < 4; i++) {
            int c = tid + i * 512;
            int m = c & 31, hh = (c >> 5) & 1, s = (c >> 6) & 7, g = c >> 9;
            int row = rowBase + g * 32 + m;
            if (row >= N) row = N - 1;
            int kc = s * 2 + hh;
            ((uint4*)Alds)[c] = *(const uint4*)(Ap + (size_t)row * stride + aoff + kc * 8);
            ((uint4*)Blds)[c] = Bsrc[c];
        }
        __syncthreads();
#pragma unroll
        for (int s = 0; s < 8; s++) {
            short8 a0 = *(const short8*)&Alds[((wm * 8 + s) * 64 + lane) * 8];
            short8 b0 = *(const short8*)&Blds[(((wn * 2 + 0) * 8 + s) * 64 + lane) * 8];
            short8 b1f = *(const short8*)&Blds[(((wn * 2 + 1) * 8 + s) * 64 + lane) * 8];
            acc[0] = __builtin_amdgcn_mfma_f32_32x32x16_bf16(a0, b0, acc[0], 0, 0, 0);
            acc[1] = __builtin_amdgcn_mfma_f32_32x32x16_bf16(a0, b1f, acc[1], 0, 0, 0);
        }
        __syncthreads();
    }

    // ---- epilogue-1: h-tile (bias+relu) -> Alds in A-fragment layout,
    //      plus B2 stage (48KB) over the B region. Both safe post-barrier.
    {
        const int qr = 4 * (lane >> 5);
        const int cl = lane & 31;
#pragma unroll
        for (int nt = 0; nt < 2; nt++) {
            float bb = b1[wn * 64 + nt * 32 + cl];
            int col = wn * 64 + nt * 32 + cl;
            int kc = col >> 3, j = col & 7;
            int s = kc >> 1, hh = kc & 1;
            int base = ((wm * 8 + s) * 64 + hh * 32) * 8 + j;
#pragma unroll
            for (int reg = 0; reg < 16; reg++) {
                int rl = (reg & 3) + 8 * (reg >> 2) + qr;
                float v = fmaxf(acc[nt][reg] + bb, 0.f);
                Alds[base + rl * 8] = f2bf(v);
            }
        }
        const uint4* B2s = (const uint4*)Bpk2;
#pragma unroll
        for (int i = 0; i < 6; i++) {
            int c = tid + i * 512;
            ((uint4*)Blds)[c] = B2s[c];
        }
    }
    __syncthreads();

    // ---- phase 2: K=128, 192 cols (wn covers 96 cols = 3 tiles of 32)
    floatx16 acc2[3] = {};
#pragma unroll
    for (int s = 0; s < 8; s++) {
        short8 a0 = *(const short8*)&Alds[((wm * 8 + s) * 64 + lane) * 8];
        short8 b0 = *(const short8*)&Blds[(((wn * 3 + 0) * 8 + s) * 64 + lane) * 8];
        short8 b1v = *(const short8*)&Blds[(((wn * 3 + 1) * 8 + s) * 64 + lane) * 8];
        short8 b2v = *(const short8*)&Blds[(((wn * 3 + 2) * 8 + s) * 64 + lane) * 8];
        acc2[0] = __builtin_amdgcn_mfma_f32_32x32x16_bf16(a0, b0, acc2[0], 0, 0, 0);
        acc2[1] = __builtin_amdgcn_mfma_f32_32x32x16_bf16(a0, b1v, acc2[1], 0, 0, 0);
        acc2[2] = __builtin_amdgcn_mfma_f32_32x32x16_bf16(a0, b2v, acc2[2], 0, 0, 0);
    }
    __syncthreads();

    // ---- epilogue-2: transpose via Clds (128 x 200 = 51.2KB, fits 80KB)
    ushort* Clds = SH;
    {
        const int qr = 4 * (lane >> 5);
        const int cl = lane & 31;
#pragma unroll
        for (int nt = 0; nt < 3; nt++) {
#pragma unroll
            for (int reg = 0; reg < 16; reg++) {
                int rl = (reg & 3) + 8 * (reg >> 2) + qr;
                Clds[(wm * 32 + rl) * 200 + wn * 96 + nt * 32 + cl] =
                    f2bf(acc2[nt][reg]);
            }
        }
    }
    __syncthreads();

    int r = tid >> 2, q4 = tid & 3;       // 4 threads per row, 48 cols each
    int grow = rowBase + r;
    if (grow < N) {
#pragma unroll
        for (int k = 0; k < 6; k++) {
            int c0 = q4 * 48 + k * 8;
            uint4 v = *(const uint4*)&Clds[r * 200 + c0];
            *(uint4*)(Out + (size_t)grow * 192 + c0) = v;
        }
    }
}

// ------- layer-2 fused: gather-mean of t2 + root + bias + L2 norm ----------

__global__ __launch_bounds__(256)
void k_final(const ushort* __restrict__ T2, const float* __restrict__ b2,
             const int* __restrict__ offs, const int* __restrict__ esrc,
             float* __restrict__ out, int N) {
    int wid = (int)((blockIdx.x * 256L + threadIdx.x) >> 3);
    int c = threadIdx.x & 7;
    if (wid >= N) return;
    const uint4* Tb = (const uint4*)T2;   // row stride 24 uint4

    int beg0 = (wid == 0) ? 0 : offs[2 * wid - 1];
    int end0 = offs[2 * wid], end1 = offs[2 * wid + 1];

    f32x2 t0 = {0.f, 0.f}, t1 = {0.f, 0.f}, t2v = {0.f, 0.f}, t3v = {0.f, 0.f};
#pragma unroll
    for (int r = 0; r < 2; r++) {
        int beg = r ? end0 : beg0;
        int end = r ? end1 : end0;
        if (end > beg) {
            f32x2 a0 = {0.f, 0.f}, a1 = {0.f, 0.f}, a2 = {0.f, 0.f}, a3 = {0.f, 0.f};
            uint bc = 8u + 8u * (uint)r + (uint)c;
            for (int c0 = beg; c0 < end; c0 += 8) {
                int myid = (c0 + c < end) ? __builtin_nontemporal_load(&esrc[c0 + c]) : N;
                int m = min(8, end - c0);
                for (int eb = 0; eb < m; eb += 4) {
                    uint4 v[4];
#pragma unroll
                    for (int j = 0; j < 4; j++) {
                        int id = __shfl(myid, eb + j, 8);
                        v[j] = Tb[(uint)id * 24u + bc];
                    }
#pragma unroll
                    for (int j = 0; j < 4; j++) {
                        a0 += (f32x2){bflo(v[j].x), bfhi(v[j].x)};
                        a1 += (f32x2){bflo(v[j].y), bfhi(v[j].y)};
                        a2 += (f32x2){bflo(v[j].z), bfhi(v[j].z)};
                        a3 += (f32x2){bflo(v[j].w), bfhi(v[j].w)};
                    }
                }
            }
            float inv = 1.0f / (float)(end - beg);
            t0 += a0 * inv; t1 += a1 * inv; t2v += a2 * inv; t3v += a3 * inv;
        }
    }
    uint4 ru = Tb[(uint)wid * 24u + (uint)c];
    float4 bbA = *(const float4*)(b2 + 8 * c);
    float4 bbB = *(const float4*)(b2 + 8 * c + 4);
    float v0 = bflo(ru.x) + bbA.x + t0.x;
    float v1 = bfhi(ru.x) + bbA.y + t0.y;
    float v2 = bflo(ru.y) + bbA.z + t1.x;
    float v3 = bfhi(ru.y) + bbA.w + t1.y;
    float v4 = bflo(ru.z) + bbB.x + t2v.x;
    float v5 = bfhi(ru.z) + bbB.y + t2v.y;
    float v6 = bflo(ru.w) + bbB.z + t3v.x;
    float v7 = bfhi(ru.w) + bbB.w + t3v.y;
    float sq = v0 * v0 + v1 * v1 + v2 * v2 + v3 * v3
             + v4 * v4 + v5 * v5 + v6 * v6 + v7 * v7;
#pragma unroll
    for (int d = 1; d <= 4; d <<= 1) sq += __shfl_xor(sq, d, 8);
    float rn = 1.0f / fmaxf(sqrtf(sq), 1e-12f);
    f32x4 oA = {v0 * rn, v1 * rn, v2 * rn, v3 * rn};
    f32x4 oB = {v4 * rn, v5 * rn, v6 * rn, v7 * rn};
    f32x4* op = (f32x4*)(out + (size_t)wid * 64 + 8 * c);
    __builtin_nontemporal_store(oA, op);
    __builtin_nontemporal_store(oB, op + 1);
}

// ---------------- launch ----------------

extern "C" void kernel_launch(void* const* d_in, const int* in_sizes, int n_in,
                              void* d_out, int out_size, void* d_ws, size_t ws_size,
                              hipStream_t stream) {
    const float* x      = (const float*)d_in[0];
    const int*   ei     = (const int*)d_in[1];
    const int*   etype  = (const int*)d_in[2];
    const float* W1rel  = (const float*)d_in[3];
    const float* W1root = (const float*)d_in[4];
    const float* b1     = (const float*)d_in[5];
    const float* W2rel  = (const float*)d_in[6];
    const float* W2root = (const float*)d_in[7];
    const float* b2     = (const float*)d_in[8];
    float* out = (float*)d_out;

    const int N = in_sizes[0] / IN_CH;   // 100000
    const int E = in_sizes[2];           // 1600000
    const int NKEY = 2 * N;
    const int NBK  = (NKEY + KPB - 1) / KPB;   // 391 buckets
    const int NBLK = (E + EPB - 1) / EPB;      // 196 partition blocks
    const int NSC  = NBK * NBLK;

    const int* src = ei;
    const int* dst = ei + E;

    char* base = (char*)d_ws;
    size_t off = 0;
    auto carve = [&](size_t bytes) -> void* {
        void* p = base + off;
        off = (off + bytes + 511) & ~(size_t)511;
        return p;
    };
    ushort* xb    = (ushort*)carve((size_t)(N + 1) * 128 * sizeof(ushort)); // +zero row
    ushort* S1    = (ushort*)carve((size_t)N * 256 * sizeof(ushort));       // 51.2MB
    ushort* t2    = (ushort*)carve((size_t)(N + 1) * 192 * sizeof(ushort)); // +zero row
    int*    esrc  = (int*)carve((size_t)E * sizeof(int));
    uint*   stage = (uint*)carve((size_t)E * sizeof(uint));                 // 6.4MB
    int*    offs  = (int*)carve((size_t)NBK * KPB * sizeof(int));
    int*    cntblk= (int*)carve((size_t)NSC * sizeof(int));
    int*    basebb= (int*)carve((size_t)(NSC + 1) * sizeof(int));
    int     NB    = (NSC + SCAN_CHUNK - 1) / SCAN_CHUNK;
    int*    bsums = (int*)carve((size_t)NB * sizeof(int));
    uint4*  Bpk1  = (uint4*)carve(6144 * sizeof(uint4));
    uint4*  Bpk2  = (uint4*)carve(4096 * sizeof(uint4));
    (void)ws_size; (void)n_in; (void)out_size;

    int n8 = N * 16;
    int preBlocks = NBLK + 40 + (n8 + 255) / 256;

    // count + cvt + prep + zero rows (count overlaps cvt/prep)
    k_pre<<<preBlocks, 256, 0, stream>>>(dst, etype, cntblk, E, NBK, NBLK,
                                         x, (uint4*)xb, n8,
                                         W1root, W1rel, W2root, W2rel,
                                         Bpk1, Bpk2,
                                         (uint*)(xb + (size_t)N * 128),
                                         (uint*)(t2 + (size_t)N * 192));

    // radix partition + fine sort
    k_scan_a<<<NB, 256, 0, stream>>>(cntblk, basebb, bsums, NSC);
    k_scan_b<<<1, 64, 0, stream>>>(bsums, basebb, NB, NSC);
    k_part<<<NBLK, 256, 0, stream>>>(src, dst, etype, basebb, bsums, stage, E, NBK, NBLK);
    k_fine<<<NBK, 256, 0, stream>>>(stage, basebb, bsums, offs, esrc, E, NBK, NBLK);

    int rowTiles = (N + 127) / 128;
    int aggBlocks = (N + 7) / 8;         // 2 nodes/wave, 8 nodes/block
    int finBlocks = (N + 31) / 32;       // 8 nodes/wave, 32 nodes/block

    // Layer 1 gather, then fused GEMM1+GEMMT -> t2 (h never hits memory)
    k_agg<<<aggBlocks, 256, 0, stream>>>(offs, esrc, (const uint4*)xb, (uint4*)S1, N);
    k_fused<<<rowTiles, 512, 0, stream>>>(xb, S1, (const ushort*)Bpk1, b1,
                                          (const ushort*)Bpk2, t2, N);

    // Layer 2 fused gather + L2 norm
    k_final<<<finBlocks, 256, 0, stream>>>(t2, b2, offs, esrc, out, N);
}